// Round 9
// baseline (128.257 us; speedup 1.0000x reference)
//
#include <hip/hip_runtime.h>
#include <hip/hip_bf16.h>
#include <math.h>

#define M_ROWS 65536
#define NSPLINE 32
#define BM 64            // rows per block
#define WROWS 16         // rows per wave
#define GROUP 4          // splines per iteration
#define SPB 16           // splines per block (y-split)
#define NITER (SPB / GROUP)       // 4
#define YS 34            // LDS halfword stride (17*even lane -> 2-way only)
#define WB_ELEMS (32 * 3 * 2 * 64 * 8)   // 98304 fp16

typedef __attribute__((ext_vector_type(8))) _Float16 half8;
typedef __attribute__((ext_vector_type(4))) float floatx4;

// Accurate-enough softplus: log(1+e^t) = t/2 + log(2*cosh(t/2)).
// Even Taylor in u=t^2 through u^4; |err| <= ~5e-6 for |t| <= 1.1.
// Exact log1pf fallback outside (P ~ 1e-7 per eval).  [R5-proven]
__device__ __forceinline__ float softplus_fast(float t) {
    float u = t * t;
    if (u > 1.21f) return log1pf(__expf(t));   // rare, exact
    float p = fmaf(u, -2.6352e-5f, 3.4722222e-4f);
    p = fmaf(u, p, -5.2083333e-3f);
    p = fmaf(u, p, 0.125f);
    p = fmaf(u, p, 0.69314718f);
    return fmaf(t, 0.5f, p);
}

// ---------------------------------------------------------------------------
// Pack W (48x1056 fp32) + bias (1056) into MFMA B-fragment layout, fp16.
// Thread = destination element (gather form, covers ALL of WH -> no memset).
// WH[sp][t][half][lane][j]:
//   k  = half*32 + (lane>>4)*8 + j   (k<48: W[k][col]; k==48: bias; else 0)
//   cl = t*16 + (lane&15), col = sp*33+cl  (cl>=33 -> zero pad)
// ---------------------------------------------------------------------------
__global__ void pack_W(const float* __restrict__ W, const float* __restrict__ b,
                       _Float16* __restrict__ WH) {
    int idx = blockIdx.x * 256 + threadIdx.x;     // < 98304
    int j    = idx & 7;
    int lane = (idx >> 3) & 63;
    int half = (idx >> 9) & 1;
    int tmp  = idx >> 10;
    int t    = tmp % 3;
    int sp   = tmp / 3;
    int k  = half * 32 + ((lane >> 4) << 3) + j;
    int cl = t * 16 + (lane & 15);
    float v = 0.0f;
    if (cl < 33 && k <= 48) {
        int col = sp * 33 + cl;
        v = (k < 48) ? W[k * 1056 + col] : b[col];
    }
    WH[idx] = (_Float16)v;
}

// ---------------------------------------------------------------------------
// Fused: fp16 MFMA GEMM (y = [z2,c,1] @ [W;b]) -> fp16 LDS transpose ->
// spline (R5-proven numerics). Grid (1024, 2): blockIdx.y picks 16 of the
// 32 splines, doubling the block count so 8 blocks/CU = 32 waves/CU fit
// (R8 was grid-limited to 4 blocks/CU = 50% wave capacity).
// No waves-per-EU floor (R6/R7: the floor makes the allocator spill).
// ---------------------------------------------------------------------------
__global__ void __launch_bounds__(256) fused_kernel(
    const float* __restrict__ z, const float* __restrict__ c,
    const _Float16* __restrict__ WH, float* __restrict__ out)
{
    __shared__ _Float16 lds_y[4 * 64 * YS];      // 17408 B

    const int tid  = threadIdx.x;
    const int w    = tid >> 6;
    const int lane = tid & 63;
    const int q    = lane >> 4;        // quad 0..3
    const int cc   = lane & 15;
    const int row_base = blockIdx.x * BM + w * WROWS;
    const int sp_base  = blockIdx.y * SPB;
    _Float16* lds_wv = lds_y + w * (64 * YS);

    // ---- z2 passthrough (only the y==0 half-grid) -------------------------
    if (blockIdx.y == 0) {
        #pragma unroll
        for (int it = 0; it < 2; ++it) {
            int idx = it * 64 + lane;             // 0..127 = 16 rows x 8 float4
            int rr  = row_base + (idx >> 3);
            int v4  = idx & 7;
            float4 val = *(const float4*)(z + (size_t)rr * 64 + 32 + v4 * 4);
            *(float4*)(out + (size_t)rr * 64 + v4 * 4) = val;
        }
    }

    // ---- A fragments (fp16, persist): A[m=cc][k], k=(q*8+j) ---------------
    half8 a0, a1;
    {
        const float* zr = z + (size_t)(row_base + cc) * 64 + 32;
        float4 v0 = *(const float4*)(zr + q * 8);
        float4 v1 = *(const float4*)(zr + q * 8 + 4);
        a0[0]=(_Float16)v0.x; a0[1]=(_Float16)v0.y;
        a0[2]=(_Float16)v0.z; a0[3]=(_Float16)v0.w;
        a0[4]=(_Float16)v1.x; a0[5]=(_Float16)v1.y;
        a0[6]=(_Float16)v1.z; a0[7]=(_Float16)v1.w;
        if (q < 2) {
            const float* cr = c + (size_t)(row_base + cc) * 16 + q * 8;
            float4 u0 = *(const float4*)cr;
            float4 u1 = *(const float4*)(cr + 4);
            a1[0]=(_Float16)u0.x; a1[1]=(_Float16)u0.y;
            a1[2]=(_Float16)u0.z; a1[3]=(_Float16)u0.w;
            a1[4]=(_Float16)u1.x; a1[5]=(_Float16)u1.y;
            a1[6]=(_Float16)u1.z; a1[7]=(_Float16)u1.w;
        } else {
            #pragma unroll
            for (int j = 0; j < 8; ++j) a1[j] = (_Float16)0.0f;
            if (q == 2) a1[0] = (_Float16)1.0f;   // k=48 bias row
        }
    }

    float ld_acc = 0.0f;

    #pragma unroll 1
    for (int g = 0; g < NITER; ++g) {
        __syncthreads();   // prior iteration's LDS reads are done

        // ---- GEMM: 4 splines x 3 col-tiles, 2 MFMA each ------------------
        #pragma unroll
        for (int sp = 0; sp < GROUP; ++sp) {
            const int spg = sp_base + g * GROUP + sp;
            #pragma unroll
            for (int t = 0; t < 3; ++t) {
                const half8* p = (const half8*)WH + (size_t)(spg * 3 + t) * 128 + lane;
                half8 b0 = p[0];
                half8 b1 = p[64];
                floatx4 acc = {0.f, 0.f, 0.f, 0.f};
                acc = __builtin_amdgcn_mfma_f32_16x16x32_f16(a0, b0, acc, 0, 0, 0);
                acc = __builtin_amdgcn_mfma_f32_16x16x32_f16(a1, b1, acc, 0, 0, 0);
                // D layout: row(m) = q*4 + reg, col(n) = cc
                if (t < 2 || cc == 0) {
                    _Float16* dst = lds_wv + (sp * 16 + q * 4) * YS + t * 16 + cc;
                    dst[0]      = (_Float16)acc[0];
                    dst[YS]     = (_Float16)acc[1];
                    dst[2 * YS] = (_Float16)acc[2];
                    dst[3 * YS] = (_Float16)acc[3];
                }
            }
        }
        __syncthreads();

        // ---- spline: task = (row=cc, spline n), all 64 lanes busy --------
        const int n = sp_base + g * GROUP + q;
        const _Float16* my = lds_wv + (q * 16 + cc) * YS;     // = lane*34
        const float in = z[(size_t)(row_base + cc) * 64 + n];

        float wd[16];
        float sew = 0.f;
        #pragma unroll
        for (int i = 0; i < 16; ++i) {
            float e = __expf((float)my[17 + i]);
            wd[i] = e; sew += e;
        }
        const float inv_sew = 0.984f / sew;        // (1 - 16*MIN_BW)/sum
        #pragma unroll
        for (int i = 0; i < 16; ++i) wd[i] = 0.001f + wd[i] * inv_sew;

        float h[17];
        #pragma unroll
        for (int i = 0; i < 17; ++i)
            h[i] = softplus_fast((float)my[i]) + 0.001f;

        float area = 0.f;
        #pragma unroll
        for (int i = 0; i < 16; ++i) area += (h[i] + h[i + 1]) * 0.5f * wd[i];
        const float inv_area = 0.999f / area;      // (1 - MIN_BH)/area
        #pragma unroll
        for (int i = 0; i < 17; ++i) h[i] = 0.001f + h[i] * inv_area;

        float loc = 0.f, cdfl = 0.f;
        float sel_loc = 0.f, sel_w = wd[0], sel_cdf = 0.f;
        float sel_lh = h[0], sel_rh = h[1];
        #pragma unroll
        for (int bn = 1; bn < 16; ++bn) {
            cdfl = fmaf((h[bn - 1] + h[bn]) * 0.5f, wd[bn - 1], cdfl);
            loc += wd[bn - 1];
            if (in >= loc) {                        // monotone: last true wins
                sel_loc = loc; sel_w = wd[bn]; sel_cdf = cdfl;
                sel_lh = h[bn]; sel_rh = h[bn + 1];
            }
        }

        const float alpha = (in - sel_loc) / sel_w;
        const float dh    = sel_rh - sel_lh;
        float o = ((0.5f * dh * sel_w) * alpha + sel_lh * sel_w) * alpha + sel_cdf;
        o = fminf(fmaxf(o, 0.0f), 1.0f);
        out[(size_t)(row_base + cc) * 64 + 32 + n] = o;
        ld_acc += __logf(fmaf(alpha, dh, sel_lh));
    }

    // ---- logdet: lanes {cc, cc+16, cc+32, cc+48} hold row cc's partials ---
    // two blocks (y=0,1) contribute per row -> atomic onto zeroed region
    ld_acc += __shfl_down(ld_acc, 32, 64);
    ld_acc += __shfl_down(ld_acc, 16, 64);
    if (q == 0)
        atomicAdd(out + (size_t)M_ROWS * 64 + row_base + cc, ld_acc);
}

extern "C" void kernel_launch(void* const* d_in, const int* in_sizes, int n_in,
                              void* d_out, int out_size, void* d_ws, size_t ws_size,
                              hipStream_t stream) {
    const float* c = (const float*)d_in[0];   // (M, 16)
    const float* z = (const float*)d_in[1];   // (M, 64)
    const float* W = (const float*)d_in[2];   // (48, 1056)
    const float* b = (const float*)d_in[3];   // (1056,)
    float* out = (float*)d_out;               // M*64 (x) then M (logdet)
    _Float16* WH = (_Float16*)d_ws;           // 98304 fp16 = 192 KiB

    hipMemsetAsync(out + (size_t)M_ROWS * 64, 0, M_ROWS * sizeof(float), stream);
    pack_W<<<WB_ELEMS / 256, 256, 0, stream>>>(W, b, WH);
    fused_kernel<<<dim3(M_ROWS / BM, 2), 256, 0, stream>>>(z, c, WH, out);
}

// Round 10
// 122.397 us; speedup vs baseline: 1.0479x; 1.0479x over previous
//
#include <hip/hip_runtime.h>
#include <hip/hip_bf16.h>
#include <math.h>

#define M_ROWS 65536
#define NSPLINE 32
#define BM 64            // rows per block
#define WROWS 16         // rows per wave
#define GROUP 4          // splines per iteration
#define NITER (NSPLINE / GROUP)   // 8
#define YS 40            // halfwords per task slot: 33 used, 40 -> 80B (16B-aligned)
#define WB_ELEMS (32 * 3 * 2 * 64 * 8)   // 98304 fp16

typedef __attribute__((ext_vector_type(8))) _Float16 half8;
typedef __attribute__((ext_vector_type(4))) _Float16 half4;
typedef __attribute__((ext_vector_type(4))) float floatx4;

// Accurate-enough softplus: log(1+e^t) = t/2 + log(2*cosh(t/2)).
// Even Taylor in u=t^2 through u^4; |err| <= ~5e-6 for |t| <= 1.1.
// Exact log1pf fallback outside (P ~ 1e-7 per eval).  [R5/R8-proven]
__device__ __forceinline__ float softplus_fast(float t) {
    float u = t * t;
    if (u > 1.21f) return log1pf(__expf(t));   // rare, exact
    float p = fmaf(u, -2.6352e-5f, 3.4722222e-4f);
    p = fmaf(u, p, -5.2083333e-3f);
    p = fmaf(u, p, 0.125f);
    p = fmaf(u, p, 0.69314718f);
    return fmaf(t, 0.5f, p);
}

// ---------------------------------------------------------------------------
// Pack W (48x1056 fp32) + bias (1056) into MFMA fragment layout, fp16.
// WH[sp][t][half][lane][j]:
//   k  = half*32 + (lane>>4)*8 + j   (k<48: W[k][col]; k==48: bias; else 0)
//   cl = t*16 + (lane&15), col = sp*33+cl  (cl>=33 -> zero pad)
// Used as the *A* operand now (m = param = lane&15) — A and B fragment
// layouts are identical for 16x16x32, so the pack is unchanged from R8.
// ---------------------------------------------------------------------------
__global__ void pack_W(const float* __restrict__ W, const float* __restrict__ b,
                       _Float16* __restrict__ WH) {
    int idx = blockIdx.x * 256 + threadIdx.x;     // < 98304
    int j    = idx & 7;
    int lane = (idx >> 3) & 63;
    int half = (idx >> 9) & 1;
    int tmp  = idx >> 10;
    int t    = tmp % 3;
    int sp   = tmp / 3;
    int k  = half * 32 + ((lane >> 4) << 3) + j;
    int cl = t * 16 + (lane & 15);
    float v = 0.0f;
    if (cl < 33 && k <= 48) {
        int col = sp * 33 + cl;
        v = (k < 48) ? W[k * 1056 + col] : b[col];
    }
    WH[idx] = (_Float16)v;
}

// ---------------------------------------------------------------------------
// Fused: TRANSPOSED fp16 MFMA GEMM  y^T = [W;b]^T-tile . z2c^T  so that
// D[m=param][n=row]: lane (q,cc) holds 4 consecutive params of row cc.
//  -> LDS writes: 1 ds_write_b64 per tile (was 4 scattered ds_write_b16)
//  -> LDS reads: 4 ds_read_b128 + 1 u16 per task (was 33 ds_read_u16)
// R9 falsified wave-starvation (2x blocks -> no change); the serialized
// per-CU LDS pipe (~81 scalar DS instr/wave-iter) is the target here.
// Spline numerics bit-identical to R8 (passed, absmax 0.015625).
// No waves-per-EU floor (R6/R7: the floor makes the allocator spill).
// ---------------------------------------------------------------------------
__global__ void __launch_bounds__(256) fused_kernel(
    const float* __restrict__ z, const float* __restrict__ c,
    const _Float16* __restrict__ WH, float* __restrict__ out)
{
    __shared__ _Float16 lds_y[4 * 64 * YS];      // 20480 B

    const int tid  = threadIdx.x;
    const int w    = tid >> 6;
    const int lane = tid & 63;
    const int q    = lane >> 4;        // quad 0..3
    const int cc   = lane & 15;
    const int row_base = blockIdx.x * BM + w * WROWS;
    _Float16* lds_wv = lds_y + w * (64 * YS);

    // ---- z2 passthrough: out[:, :32] = z[:, 32:64] for this wave's rows ----
    #pragma unroll
    for (int it = 0; it < 2; ++it) {
        int idx = it * 64 + lane;                 // 0..127 = 16 rows x 8 float4
        int rr  = row_base + (idx >> 3);
        int v4  = idx & 7;
        float4 val = *(const float4*)(z + (size_t)rr * 64 + 32 + v4 * 4);
        *(float4*)(out + (size_t)rr * 64 + v4 * 4) = val;
    }

    // ---- z2c fragments (fp16, persist): now the *B* operand ---------------
    // B[k=(q*8+j)][n=cc] = z2c[row cc][k] — identical data/layout to R8's A.
    half8 a0, a1;
    {
        const float* zr = z + (size_t)(row_base + cc) * 64 + 32;
        float4 v0 = *(const float4*)(zr + q * 8);
        float4 v1 = *(const float4*)(zr + q * 8 + 4);
        a0[0]=(_Float16)v0.x; a0[1]=(_Float16)v0.y;
        a0[2]=(_Float16)v0.z; a0[3]=(_Float16)v0.w;
        a0[4]=(_Float16)v1.x; a0[5]=(_Float16)v1.y;
        a0[6]=(_Float16)v1.z; a0[7]=(_Float16)v1.w;
        if (q < 2) {
            const float* cr = c + (size_t)(row_base + cc) * 16 + q * 8;
            float4 u0 = *(const float4*)cr;
            float4 u1 = *(const float4*)(cr + 4);
            a1[0]=(_Float16)u0.x; a1[1]=(_Float16)u0.y;
            a1[2]=(_Float16)u0.z; a1[3]=(_Float16)u0.w;
            a1[4]=(_Float16)u1.x; a1[5]=(_Float16)u1.y;
            a1[6]=(_Float16)u1.z; a1[7]=(_Float16)u1.w;
        } else {
            #pragma unroll
            for (int j = 0; j < 8; ++j) a1[j] = (_Float16)0.0f;
            if (q == 2) a1[0] = (_Float16)1.0f;   // k=48 bias row
        }
    }

    float ld_acc = 0.0f;

    #pragma unroll 1
    for (int g = 0; g < NITER; ++g) {
        __syncthreads();   // prior iteration's LDS reads are done

        // ---- GEMM (transposed): A = W-tile (m=param), B = z2c (n=row) ----
        #pragma unroll
        for (int sp = 0; sp < GROUP; ++sp) {
            const int spg = g * GROUP + sp;
            const int task = sp * 16 + cc;        // (spline sp, row cc)
            #pragma unroll
            for (int t = 0; t < 3; ++t) {
                const half8* p = (const half8*)WH + (size_t)(spg * 3 + t) * 128 + lane;
                half8 b0 = p[0];
                half8 b1 = p[64];
                floatx4 acc = {0.f, 0.f, 0.f, 0.f};
                acc = __builtin_amdgcn_mfma_f32_16x16x32_f16(b0, a0, acc, 0, 0, 0);
                acc = __builtin_amdgcn_mfma_f32_16x16x32_f16(b1, a1, acc, 0, 0, 0);
                // D: m(param) = q*4 + reg, n(row) = cc
                if (t < 2) {
                    half4 v;
                    v[0] = (_Float16)acc[0]; v[1] = (_Float16)acc[1];
                    v[2] = (_Float16)acc[2]; v[3] = (_Float16)acc[3];
                    *(half4*)(lds_wv + task * YS + t * 16 + q * 4) = v;  // b64
                } else if (q == 0) {
                    lds_wv[task * YS + 32] = (_Float16)acc[0];  // param 32 only
                }
            }
        }
        __syncthreads();

        // ---- spline: task = (row=cc, spline n=g*4+q), all 64 lanes busy --
        const int n = g * GROUP + q;
        const _Float16* my = lds_wv + (q * 16 + cc) * YS;  // 80B-aligned
        const half8* mp = (const half8*)my;
        half8 r0 = mp[0], r1 = mp[1], r2 = mp[2], r3 = mp[3];  // 4x b128
        float pv[33];
        #pragma unroll
        for (int i = 0; i < 8; ++i) pv[i]      = (float)r0[i];
        #pragma unroll
        for (int i = 0; i < 8; ++i) pv[8 + i]  = (float)r1[i];
        #pragma unroll
        for (int i = 0; i < 8; ++i) pv[16 + i] = (float)r2[i];
        #pragma unroll
        for (int i = 0; i < 8; ++i) pv[24 + i] = (float)r3[i];
        pv[32] = (float)my[32];

        const float in = z[(size_t)(row_base + cc) * 64 + n];

        float wd[16];
        float sew = 0.f;
        #pragma unroll
        for (int i = 0; i < 16; ++i) {
            float e = __expf(pv[17 + i]);
            wd[i] = e; sew += e;
        }
        const float inv_sew = 0.984f / sew;        // (1 - 16*MIN_BW)/sum
        #pragma unroll
        for (int i = 0; i < 16; ++i) wd[i] = 0.001f + wd[i] * inv_sew;

        float h[17];
        #pragma unroll
        for (int i = 0; i < 17; ++i)
            h[i] = softplus_fast(pv[i]) + 0.001f;

        float area = 0.f;
        #pragma unroll
        for (int i = 0; i < 16; ++i) area += (h[i] + h[i + 1]) * 0.5f * wd[i];
        const float inv_area = 0.999f / area;      // (1 - MIN_BH)/area
        #pragma unroll
        for (int i = 0; i < 17; ++i) h[i] = 0.001f + h[i] * inv_area;

        float loc = 0.f, cdfl = 0.f;
        float sel_loc = 0.f, sel_w = wd[0], sel_cdf = 0.f;
        float sel_lh = h[0], sel_rh = h[1];
        #pragma unroll
        for (int bn = 1; bn < 16; ++bn) {
            cdfl = fmaf((h[bn - 1] + h[bn]) * 0.5f, wd[bn - 1], cdfl);
            loc += wd[bn - 1];
            if (in >= loc) {                        // monotone: last true wins
                sel_loc = loc; sel_w = wd[bn]; sel_cdf = cdfl;
                sel_lh = h[bn]; sel_rh = h[bn + 1];
            }
        }

        const float alpha = (in - sel_loc) / sel_w;
        const float dh    = sel_rh - sel_lh;
        float o = ((0.5f * dh * sel_w) * alpha + sel_lh * sel_w) * alpha + sel_cdf;
        o = fminf(fmaxf(o, 0.0f), 1.0f);
        out[(size_t)(row_base + cc) * 64 + 32 + n] = o;
        ld_acc += __logf(fmaf(alpha, dh, sel_lh));
    }

    // ---- logdet: lanes {cc, cc+16, cc+32, cc+48} hold row cc's partials ---
    ld_acc += __shfl_down(ld_acc, 32, 64);
    ld_acc += __shfl_down(ld_acc, 16, 64);
    if (q == 0)
        out[(size_t)M_ROWS * 64 + row_base + cc] = ld_acc;
}

extern "C" void kernel_launch(void* const* d_in, const int* in_sizes, int n_in,
                              void* d_out, int out_size, void* d_ws, size_t ws_size,
                              hipStream_t stream) {
    const float* c = (const float*)d_in[0];   // (M, 16)
    const float* z = (const float*)d_in[1];   // (M, 64)
    const float* W = (const float*)d_in[2];   // (48, 1056)
    const float* b = (const float*)d_in[3];   // (1056,)
    float* out = (float*)d_out;               // M*64 (x) then M (logdet)
    _Float16* WH = (_Float16*)d_ws;           // 98304 fp16 = 192 KiB

    pack_W<<<WB_ELEMS / 256, 256, 0, stream>>>(W, b, WH);
    fused_kernel<<<M_ROWS / BM, 256, 0, stream>>>(z, c, WH, out);
}

// Round 11
// 118.743 us; speedup vs baseline: 1.0801x; 1.0308x over previous
//
#include <hip/hip_runtime.h>
#include <hip/hip_bf16.h>
#include <math.h>

#define M_ROWS 65536
#define NSPLINE 32
#define BM 64            // rows per block
#define WROWS 16         // rows per wave
#define GROUP 4          // splines per iteration
#define NITER (NSPLINE / GROUP)   // 8
#define YS 34            // fp32 words per task slot (34%32=2 -> 2-way alias, free; 8B-aligned)
#define WB_ELEMS (32 * 3 * 2 * 64 * 8)   // 98304 fp16

typedef __attribute__((ext_vector_type(8))) _Float16 half8;
typedef __attribute__((ext_vector_type(4))) float floatx4;

// Accurate-enough softplus: log(1+e^t) = t/2 + log(2*cosh(t/2)).
// Even Taylor in u=t^2 through u^4; |err| <= ~5e-6 for |t| <= 1.1.
// Exact log1pf fallback outside (P ~ 1e-7 per eval).  [R5/R8-proven]
__device__ __forceinline__ float softplus_fast(float t) {
    float u = t * t;
    if (u > 1.21f) return log1pf(__expf(t));   // rare, exact
    float p = fmaf(u, -2.6352e-5f, 3.4722222e-4f);
    p = fmaf(u, p, -5.2083333e-3f);
    p = fmaf(u, p, 0.125f);
    p = fmaf(u, p, 0.69314718f);
    return fmaf(t, 0.5f, p);
}

// ---------------------------------------------------------------------------
// Pack W (48x1056 fp32) + bias (1056) into MFMA fragment layout, fp16.
// WH[sp][t][half][lane][j]:
//   k  = half*32 + (lane>>4)*8 + j   (k<48: W[k][col]; k==48: bias; else 0)
//   cl = t*16 + (lane&15), col = sp*33+cl  (cl>=33 -> zero pad)
// Used as the A operand (m = param = lane&15).  [unchanged from R10]
// ---------------------------------------------------------------------------
__global__ void pack_W(const float* __restrict__ W, const float* __restrict__ b,
                       _Float16* __restrict__ WH) {
    int idx = blockIdx.x * 256 + threadIdx.x;     // < 98304
    int j    = idx & 7;
    int lane = (idx >> 3) & 63;
    int half = (idx >> 9) & 1;
    int tmp  = idx >> 10;
    int t    = tmp % 3;
    int sp   = tmp / 3;
    int k  = half * 32 + ((lane >> 4) << 3) + j;
    int cl = t * 16 + (lane & 15);
    float v = 0.0f;
    if (cl < 33 && k <= 48) {
        int col = sp * 33 + cl;
        v = (k < 48) ? W[k * 1056 + col] : b[col];
    }
    WH[idx] = (_Float16)v;
}

// ---------------------------------------------------------------------------
// Fused, BARRIER-FREE: each wave's LDS region is private (it writes its own
// GEMM output and reads it back itself), so __syncthreads is unnecessary —
// the compiler's intra-wave lgkmcnt waits are the only sync needed. R10's
// 16 block-wide barriers forced all 4 waves to drain vmcnt/lgkmcnt together
// (the ~37% idle). LDS is now fp32 (kills ~100 f16<->f32 cvt per wave-iter);
// YS=34 words: float2 ops are 8B-aligned, 2-way bank alias = free.
// Spline numerics identical to R8/R10 (passed, absmax 0.015625).
// No waves-per-EU floor (R6/R7: the floor makes the allocator spill).
// ---------------------------------------------------------------------------
__global__ void __launch_bounds__(256) fused_kernel(
    const float* __restrict__ z, const float* __restrict__ c,
    const _Float16* __restrict__ WH, float* __restrict__ out)
{
    __shared__ float lds_y[4 * 64 * YS];         // 34816 B

    const int tid  = threadIdx.x;
    const int w    = tid >> 6;
    const int lane = tid & 63;
    const int q    = lane >> 4;        // quad 0..3
    const int cc   = lane & 15;
    const int row_base = blockIdx.x * BM + w * WROWS;
    float* lds_wv = lds_y + w * (64 * YS);

    // ---- z2 passthrough: out[:, :32] = z[:, 32:64] for this wave's rows ----
    #pragma unroll
    for (int it = 0; it < 2; ++it) {
        int idx = it * 64 + lane;                 // 0..127 = 16 rows x 8 float4
        int rr  = row_base + (idx >> 3);
        int v4  = idx & 7;
        float4 val = *(const float4*)(z + (size_t)rr * 64 + 32 + v4 * 4);
        *(float4*)(out + (size_t)rr * 64 + v4 * 4) = val;
    }

    // ---- z2c fragments (fp16, persist): the B operand ---------------------
    // B[k=(q*8+j)][n=cc] = z2c[row cc][k]
    half8 a0, a1;
    {
        const float* zr = z + (size_t)(row_base + cc) * 64 + 32;
        float4 v0 = *(const float4*)(zr + q * 8);
        float4 v1 = *(const float4*)(zr + q * 8 + 4);
        a0[0]=(_Float16)v0.x; a0[1]=(_Float16)v0.y;
        a0[2]=(_Float16)v0.z; a0[3]=(_Float16)v0.w;
        a0[4]=(_Float16)v1.x; a0[5]=(_Float16)v1.y;
        a0[6]=(_Float16)v1.z; a0[7]=(_Float16)v1.w;
        if (q < 2) {
            const float* cr = c + (size_t)(row_base + cc) * 16 + q * 8;
            float4 u0 = *(const float4*)cr;
            float4 u1 = *(const float4*)(cr + 4);
            a1[0]=(_Float16)u0.x; a1[1]=(_Float16)u0.y;
            a1[2]=(_Float16)u0.z; a1[3]=(_Float16)u0.w;
            a1[4]=(_Float16)u1.x; a1[5]=(_Float16)u1.y;
            a1[6]=(_Float16)u1.z; a1[7]=(_Float16)u1.w;
        } else {
            #pragma unroll
            for (int j = 0; j < 8; ++j) a1[j] = (_Float16)0.0f;
            if (q == 2) a1[0] = (_Float16)1.0f;   // k=48 bias row
        }
    }

    // ---- preload this lane's 8 spline inputs z1[row cc][n=g*4+q] ----------
    float zin[NITER];
    {
        const float* zr = z + (size_t)(row_base + cc) * 64 + q;
        #pragma unroll
        for (int g = 0; g < NITER; ++g) zin[g] = zr[g * 4];
    }

    float ld_acc = 0.0f;

    #pragma unroll 1
    for (int g = 0; g < NITER; ++g) {
        // ---- GEMM (transposed): A = W-tile (m=param), B = z2c (n=row) ----
        // D: m(param) = q*4 + reg, n(row) = cc -> lane holds 4 consecutive
        // params of task (sp,cc); write them with float2 stores (8B-aligned).
        #pragma unroll
        for (int sp = 0; sp < GROUP; ++sp) {
            const int spg = g * GROUP + sp;
            const int task = sp * 16 + cc;        // (spline sp, row cc)
            #pragma unroll
            for (int t = 0; t < 3; ++t) {
                const half8* p = (const half8*)WH + (size_t)(spg * 3 + t) * 128 + lane;
                half8 b0 = p[0];
                half8 b1 = p[64];
                floatx4 acc = {0.f, 0.f, 0.f, 0.f};
                acc = __builtin_amdgcn_mfma_f32_16x16x32_f16(b0, a0, acc, 0, 0, 0);
                acc = __builtin_amdgcn_mfma_f32_16x16x32_f16(b1, a1, acc, 0, 0, 0);
                if (t < 2) {
                    float* dst = lds_wv + task * YS + t * 16 + q * 4;
                    *(float2*)dst       = make_float2(acc[0], acc[1]);
                    *(float2*)(dst + 2) = make_float2(acc[2], acc[3]);
                } else if (q == 0) {
                    lds_wv[task * YS + 32] = acc[0];  // param 32 only
                }
            }
        }
        // no __syncthreads: LDS region is wave-private; the compiler's
        // lgkmcnt waits order this wave's ds_writes before its ds_reads.

        // ---- spline: task = lane = (row=cc, spline n=g*4+q) --------------
        const int n = g * GROUP + q;
        const float* my = lds_wv + lane * YS;
        float pv[33];
        #pragma unroll
        for (int i = 0; i < 16; ++i) {
            float2 v = *(const float2*)(my + 2 * i);
            pv[2 * i] = v.x; pv[2 * i + 1] = v.y;
        }
        pv[32] = my[32];

        const float in = zin[g];

        float wd[16];
        float sew = 0.f;
        #pragma unroll
        for (int i = 0; i < 16; ++i) {
            float e = __expf(pv[17 + i]);
            wd[i] = e; sew += e;
        }
        const float inv_sew = 0.984f / sew;        // (1 - 16*MIN_BW)/sum
        #pragma unroll
        for (int i = 0; i < 16; ++i) wd[i] = 0.001f + wd[i] * inv_sew;

        float h[17];
        #pragma unroll
        for (int i = 0; i < 17; ++i)
            h[i] = softplus_fast(pv[i]) + 0.001f;

        float area = 0.f;
        #pragma unroll
        for (int i = 0; i < 16; ++i) area += (h[i] + h[i + 1]) * 0.5f * wd[i];
        const float inv_area = 0.999f / area;      // (1 - MIN_BH)/area
        #pragma unroll
        for (int i = 0; i < 17; ++i) h[i] = 0.001f + h[i] * inv_area;

        float loc = 0.f, cdfl = 0.f;
        float sel_loc = 0.f, sel_w = wd[0], sel_cdf = 0.f;
        float sel_lh = h[0], sel_rh = h[1];
        #pragma unroll
        for (int bn = 1; bn < 16; ++bn) {
            cdfl = fmaf((h[bn - 1] + h[bn]) * 0.5f, wd[bn - 1], cdfl);
            loc += wd[bn - 1];
            if (in >= loc) {                        // monotone: last true wins
                sel_loc = loc; sel_w = wd[bn]; sel_cdf = cdfl;
                sel_lh = h[bn]; sel_rh = h[bn + 1];
            }
        }

        const float alpha = (in - sel_loc) / sel_w;
        const float dh    = sel_rh - sel_lh;
        float o = ((0.5f * dh * sel_w) * alpha + sel_lh * sel_w) * alpha + sel_cdf;
        o = fminf(fmaxf(o, 0.0f), 1.0f);
        out[(size_t)(row_base + cc) * 64 + 32 + n] = o;
        ld_acc += __logf(fmaf(alpha, dh, sel_lh));
    }

    // ---- logdet: lanes {cc, cc+16, cc+32, cc+48} hold row cc's partials ---
    ld_acc += __shfl_down(ld_acc, 32, 64);
    ld_acc += __shfl_down(ld_acc, 16, 64);
    if (q == 0)
        out[(size_t)M_ROWS * 64 + row_base + cc] = ld_acc;
}

extern "C" void kernel_launch(void* const* d_in, const int* in_sizes, int n_in,
                              void* d_out, int out_size, void* d_ws, size_t ws_size,
                              hipStream_t stream) {
    const float* c = (const float*)d_in[0];   // (M, 16)
    const float* z = (const float*)d_in[1];   // (M, 64)
    const float* W = (const float*)d_in[2];   // (48, 1056)
    const float* b = (const float*)d_in[3];   // (1056,)
    float* out = (float*)d_out;               // M*64 (x) then M (logdet)
    _Float16* WH = (_Float16*)d_ws;           // 98304 fp16 = 192 KiB

    pack_W<<<WB_ELEMS / 256, 256, 0, stream>>>(W, b, WH);
    fused_kernel<<<M_ROWS / BM, 256, 0, stream>>>(z, c, WH, out);
}